// Round 7
// baseline (359.878 us; speedup 1.0000x reference)
//
#include <hip/hip_runtime.h>
#include <cstddef>

#define Nn 50000
#define Ee 500000
#define INC 128
#define HC 256      // HEADS*OUT_C
#define OUTC 64
#define EDIM 32
#define NEG 0.2f
#define BK 32

typedef __attribute__((ext_vector_type(8))) short short8;   // 8 bf16 = 4 VGPR
typedef __attribute__((ext_vector_type(4))) float f32x4;

// ---- bf16 helpers (RNE) ----
__device__ __forceinline__ unsigned short f2bf(float f) {
    unsigned u = __float_as_uint(f);
    return (unsigned short)((u + 0x7FFFu + ((u >> 16) & 1u)) >> 16);
}
__device__ __forceinline__ float bf2f(unsigned short v) {
    return __uint_as_float(((unsigned)v) << 16);
}

// ---- ordered-uint encoding for float atomic max ----
__device__ __forceinline__ unsigned fenc(float f) {
    unsigned u = __float_as_uint(f);
    return (u & 0x80000000u) ? ~u : (u | 0x80000000u);
}
__device__ __forceinline__ float fdec(unsigned k) {
    unsigned u = (k & 0x80000000u) ? (k & 0x7FFFFFFFu) : ~k;
    return __uint_as_float(u);
}

// ---- K0: init out=bias, amax=0 (== -inf key), denom=0 ----
__global__ __launch_bounds__(256) void init_kernel(
    float* __restrict__ out, const float* __restrict__ bias,
    unsigned* __restrict__ amax, float* __restrict__ denom)
{
    int idx = blockIdx.x * 256 + threadIdx.x;
    if (idx < Nn * OUTC) out[idx] = bias[idx & (OUTC - 1)];
    if (idx < Nn * 4) { amax[idx] = 0u; denom[idx] = 0.f; }
}

// ---- K_we: pre-pack We into MFMA B-frag order, bf16, PERMUTED columns ----
// Tile (cb,nt), tile-col l15 maps to original column cb*64 + l15*4 + nt.
// This makes each lane's 4 nt-columns consecutive -> ushort4 gathers in K2.
__global__ __launch_bounds__(256) void we_frag_kernel(
    const float* __restrict__ We, unsigned short* __restrict__ wef)
{
    int sid = blockIdx.x * 256 + threadIdx.x;
    if (sid >= 1024) return;
    int lane = sid & 63, nt = (sid >> 6) & 3, cb = sid >> 8;
    int col = cb * 64 + (lane & 15) * 4 + nt;   // permuted within head block
    int k0 = (lane >> 4) * 8;
    unsigned short tmp[8];
    #pragma unroll
    for (int j = 0; j < 8; ++j) tmp[j] = f2bf(We[(size_t)(k0 + j) * HC + col]);
    *(uint4*)(wef + (size_t)sid * 8) = *(uint4*)tmp;
}

// ---- K1: Y = X @ W + b -> bf16 only (y==0 -> xlb, y==1 -> xrb) ----
__global__ __launch_bounds__(256) void gemm_kernel(
    const float* __restrict__ X,
    const float* __restrict__ Wl, const float* __restrict__ bl,
    const float* __restrict__ Wr, const float* __restrict__ br,
    unsigned short* __restrict__ Ylb, unsigned short* __restrict__ Yrb)
{
    const float* W; const float* b; unsigned short* Yb;
    if (blockIdx.y == 0) { W = Wl; b = bl; Yb = Ylb; } else { W = Wr; b = br; Yb = Yrb; }

    __shared__ float sA[64][36];
    __shared__ float sB[BK][256];

    const int row0 = blockIdx.x * 64;
    const int tid  = threadIdx.x;
    const int ty   = tid >> 4;
    const int tx   = tid & 15;

    float4 acc[4][4];
    #pragma unroll
    for (int i = 0; i < 4; ++i)
        #pragma unroll
        for (int j = 0; j < 4; ++j)
            acc[i][j] = make_float4(0.f, 0.f, 0.f, 0.f);

    #pragma unroll 1
    for (int k0 = 0; k0 < INC; k0 += BK) {
        if (k0) __syncthreads();
        #pragma unroll
        for (int it = 0; it < 2; ++it) {
            int idx = tid + it * 256;
            int r = idx >> 3, c = (idx & 7) << 2;
            float4 v = make_float4(0.f, 0.f, 0.f, 0.f);
            if (row0 + r < Nn) v = *(const float4*)(X + (size_t)(row0 + r) * INC + k0 + c);
            *(float4*)(&sA[r][c]) = v;
        }
        #pragma unroll
        for (int it = 0; it < 8; ++it) {
            int idx = tid + it * 256;
            int k = idx >> 6, c = (idx & 63) << 2;
            *(float4*)(&sB[k][c]) = *(const float4*)(W + (size_t)(k0 + k) * HC + c);
        }
        __syncthreads();

        #pragma unroll 1
        for (int kk = 0; kk < BK; kk += 4) {
            float4 a[4];
            #pragma unroll
            for (int i = 0; i < 4; ++i) a[i] = *(const float4*)(&sA[ty * 4 + i][kk]);
            #pragma unroll
            for (int t = 0; t < 4; ++t) {
                float4 bv[4];
                #pragma unroll
                for (int j = 0; j < 4; ++j)
                    bv[j] = *(const float4*)(&sB[kk + t][tx * 4 + j * 64]);
                #pragma unroll
                for (int i = 0; i < 4; ++i) {
                    float av = (t == 0) ? a[i].x : (t == 1) ? a[i].y : (t == 2) ? a[i].z : a[i].w;
                    #pragma unroll
                    for (int j = 0; j < 4; ++j) {
                        acc[i][j].x += av * bv[j].x;
                        acc[i][j].y += av * bv[j].y;
                        acc[i][j].z += av * bv[j].z;
                        acc[i][j].w += av * bv[j].w;
                    }
                }
            }
        }
    }

    float4 bs[4];
    #pragma unroll
    for (int j = 0; j < 4; ++j) bs[j] = *(const float4*)(b + tx * 4 + j * 64);
    #pragma unroll
    for (int i = 0; i < 4; ++i) {
        int grow = row0 + ty * 4 + i;
        if (grow < Nn) {
            #pragma unroll
            for (int j = 0; j < 4; ++j) {
                float4 o = make_float4(acc[i][j].x + bs[j].x, acc[i][j].y + bs[j].y,
                                       acc[i][j].z + bs[j].z, acc[i][j].w + bs[j].w);
                ushort4 ob;
                ob.x = f2bf(o.x); ob.y = f2bf(o.y); ob.z = f2bf(o.z); ob.w = f2bf(o.w);
                *(ushort4*)(Yb + (size_t)grow * HC + tx * 4 + j * 64) = ob;
            }
        }
    }
}

// ---- K2: per-edge logits via MFMA bf16, no LDS, permuted-column gathers ----
// Block = 128 edges = 4 waves x 32 edges (2 M-tiles). acc[mt][nt][r] holds the
// e-term for orig col cb*64 + l15*4 + nt -> one ushort4 gather per (slot,cb,arr).
__global__ __launch_bounds__(256) void edge_alpha_kernel(
    const unsigned short* __restrict__ xlb, const unsigned short* __restrict__ xrb,
    const int* __restrict__ ei, const float* __restrict__ ea,
    const unsigned short* __restrict__ wef, const float* __restrict__ att,
    float* __restrict__ alpha, unsigned* __restrict__ amax)
{
    const int tid  = threadIdx.x;
    const int lane = tid & 63;
    const int l15  = lane & 15, l4 = lane >> 4;
    const int e0   = blockIdx.x * 128 + (tid >> 6) * 32;

    // A-frags: 2 tiles of 16 edges; lane holds ea[e0+mt*16+l15][l4*8 .. +7]
    // nontemporal: ea is streamed once; keep it out of L3 so xlb/xrb stay resident
    short8 afrag[2];
    #pragma unroll
    for (int mt = 0; mt < 2; ++mt) {
        int e = e0 + mt * 16 + l15;
        if (e >= Ee) e = 0;
        const f32x4* p = (const f32x4*)(ea + (size_t)e * EDIM + l4 * 8);
        f32x4 v0 = __builtin_nontemporal_load(p);
        f32x4 v1 = __builtin_nontemporal_load(p + 1);
        short8 a;
        a[0] = (short)f2bf(v0.x); a[1] = (short)f2bf(v0.y);
        a[2] = (short)f2bf(v0.z); a[3] = (short)f2bf(v0.w);
        a[4] = (short)f2bf(v1.x); a[5] = (short)f2bf(v1.y);
        a[6] = (short)f2bf(v1.z); a[7] = (short)f2bf(v1.w);
        afrag[mt] = a;
    }

    // per-slot edge ids and node row offsets (slot = mt*4 + r)
    unsigned soff[8], doff[8];
    #pragma unroll
    for (int mt = 0; mt < 2; ++mt)
        #pragma unroll
        for (int r = 0; r < 4; ++r) {
            int idx = mt * 4 + r;
            int e = e0 + mt * 16 + l4 * 4 + r;
            int ec = (e < Ee) ? e : 0;
            soff[idx] = (unsigned)ei[ec] * (unsigned)HC;
            doff[idx] = (unsigned)ei[Ee + ec] * (unsigned)HC;
        }

    // att for this lane's 4 consecutive columns per head block
    float4 attv[4];
    #pragma unroll
    for (int cb = 0; cb < 4; ++cb)
        attv[cb] = *(const float4*)(att + cb * 64 + l15 * 4);

    #pragma unroll 1
    for (int cb = 0; cb < 4; ++cb) {
        short8 bfrag[4];
        #pragma unroll
        for (int nt = 0; nt < 4; ++nt)
            bfrag[nt] = *(const short8*)(wef + ((size_t)(cb * 4 + nt) * 64 + lane) * 8);

        f32x4 acc[2][4];
        const f32x4 z = {0.f, 0.f, 0.f, 0.f};
        #pragma unroll
        for (int mt = 0; mt < 2; ++mt)
            #pragma unroll
            for (int nt = 0; nt < 4; ++nt)
                acc[mt][nt] = __builtin_amdgcn_mfma_f32_16x16x32_bf16(
                    afrag[mt], bfrag[nt], z, 0, 0, 0);

        #pragma unroll
        for (int mt = 0; mt < 2; ++mt) {
            #pragma unroll
            for (int r = 0; r < 4; ++r) {
                const int idx = mt * 4 + r;
                const unsigned c = (unsigned)(cb * 64 + l15 * 4);
                ushort4 gl4 = *(const ushort4*)(xlb + soff[idx] + c);
                ushort4 gr4 = *(const ushort4*)(xrb + doff[idx] + c);
                float m0 = acc[mt][0][r] + bf2f(gl4.x) + bf2f(gr4.x);
                float m1 = acc[mt][1][r] + bf2f(gl4.y) + bf2f(gr4.y);
                float m2 = acc[mt][2][r] + bf2f(gl4.z) + bf2f(gr4.z);
                float m3 = acc[mt][3][r] + bf2f(gl4.w) + bf2f(gr4.w);
                m0 = fmaxf(m0, NEG * m0);
                m1 = fmaxf(m1, NEG * m1);
                m2 = fmaxf(m2, NEG * m2);
                m3 = fmaxf(m3, NEG * m3);
                float p;
                p = attv[cb].x * m0;
                p = fmaf(attv[cb].y, m1, p);
                p = fmaf(attv[cb].z, m2, p);
                p = fmaf(attv[cb].w, m3, p);
                p += __shfl_xor(p, 1, 64);
                p += __shfl_xor(p, 2, 64);
                p += __shfl_xor(p, 4, 64);
                p += __shfl_xor(p, 8, 64);
                int e = e0 + mt * 16 + l4 * 4 + r;
                if (l15 == 0 && e < Ee) {
                    alpha[(size_t)e * 4 + cb] = p;
                    atomicMax(amax + (size_t)(doff[idx] >> 8) * 4 + cb, fenc(p));
                }
            }
        }
    }
}

// ---- K3: alpha <- exp(alpha - amax[dst]); denom[dst] += alpha ----
__global__ __launch_bounds__(256) void edge_exp_kernel(
    const int* __restrict__ ei, float* __restrict__ alpha,
    const unsigned* __restrict__ amax, float* __restrict__ denom)
{
    int idx = blockIdx.x * 256 + threadIdx.x;
    if (idx >= Ee * 4) return;
    int e = idx >> 2, h = idx & 3;
    int d = ei[Ee + e];
    float mx = fdec(amax[(size_t)d * 4 + h]);
    float v = __expf(alpha[idx] - mx);
    alpha[idx] = v;
    atomicAdd(denom + (size_t)d * 4 + h, v);
}

// ---- K4: out[dst,c] += 0.25 * sum_h (alpha/denom) * xlb[src,h,c] (bf16 gather) ----
__global__ __launch_bounds__(256) void edge_aggr_kernel(
    const unsigned short* __restrict__ xlb, const int* __restrict__ ei,
    const float* __restrict__ alpha, const float* __restrict__ denom,
    float* __restrict__ out)
{
    int lane = threadIdx.x & 63;
    int e = blockIdx.x * 4 + (threadIdx.x >> 6);
    if (e >= Ee) return;
    int s = ei[e], d = ei[Ee + e];
    float acc = 0.f;
    #pragma unroll
    for (int h = 0; h < 4; ++h) {
        float w = 0.25f * alpha[(size_t)e * 4 + h] / denom[(size_t)d * 4 + h];
        acc = fmaf(w, bf2f(xlb[(size_t)s * HC + h * OUTC + lane]), acc);
    }
    atomicAdd(out + (size_t)d * OUTC + lane, acc);
}

extern "C" void kernel_launch(void* const* d_in, const int* in_sizes, int n_in,
                              void* d_out, int out_size, void* d_ws, size_t ws_size,
                              hipStream_t stream)
{
    const float* x    = (const float*)d_in[0];
    const int*   ei   = (const int*)d_in[1];
    const float* ea   = (const float*)d_in[2];
    const float* Wl   = (const float*)d_in[3];
    const float* bl   = (const float*)d_in[4];
    const float* Wr   = (const float*)d_in[5];
    const float* br   = (const float*)d_in[6];
    const float* We   = (const float*)d_in[7];
    const float* att  = (const float*)d_in[8];
    const float* bias = (const float*)d_in[9];
    float* out = (float*)d_out;

    // workspace layout (~61 MB)
    unsigned short* xlb   = (unsigned short*)d_ws;                 // N*256 bf16
    unsigned short* xrb   = xlb + (size_t)Nn * HC;                 // N*256 bf16
    float*          alpha = (float*)(xrb + (size_t)Nn * HC);       // E*4
    unsigned*       amax  = (unsigned*)(alpha + (size_t)Ee * 4);   // N*4
    float*          denom = (float*)(amax + (size_t)Nn * 4);       // N*4
    unsigned short* wef   = (unsigned short*)(denom + (size_t)Nn * 4); // 8192 bf16

    init_kernel<<<(Nn * OUTC + 255) / 256, 256, 0, stream>>>(out, bias, amax, denom);
    we_frag_kernel<<<4, 256, 0, stream>>>(We, wef);
    gemm_kernel<<<dim3((Nn + 63) / 64, 2), 256, 0, stream>>>(x, Wl, bl, Wr, br, xlb, xrb);
    edge_alpha_kernel<<<(Ee + 127) / 128, 256, 0, stream>>>(xlb, xrb, ei, ea, wef, att, alpha, amax);
    edge_exp_kernel<<<(Ee * 4 + 255) / 256, 256, 0, stream>>>(ei, alpha, amax, denom);
    edge_aggr_kernel<<<(Ee + 3) / 4, 256, 0, stream>>>(xlb, ei, alpha, denom, out);
}

// Round 8
// 332.903 us; speedup vs baseline: 1.0810x; 1.0810x over previous
//
#include <hip/hip_runtime.h>
#include <cstddef>

#define Nn 50000
#define Ee 500000
#define INC 128
#define HC 256      // HEADS*OUT_C
#define OUTC 64
#define EDIM 32
#define NEG 0.2f

typedef __attribute__((ext_vector_type(8))) short short8;   // 8 bf16 = 4 VGPR
typedef __attribute__((ext_vector_type(4))) float f32x4;

// ---- bf16 helpers (RNE) ----
__device__ __forceinline__ unsigned short f2bf(float f) {
    unsigned u = __float_as_uint(f);
    return (unsigned short)((u + 0x7FFFu + ((u >> 16) & 1u)) >> 16);
}
__device__ __forceinline__ float bf2f(unsigned short v) {
    return __uint_as_float(((unsigned)v) << 16);
}

// ---- ordered-uint encoding for float atomic max ----
__device__ __forceinline__ unsigned fenc(float f) {
    unsigned u = __float_as_uint(f);
    return (u & 0x80000000u) ? ~u : (u | 0x80000000u);
}
__device__ __forceinline__ float fdec(unsigned k) {
    unsigned u = (k & 0x80000000u) ? (k & 0x7FFFFFFFu) : ~k;
    return __uint_as_float(u);
}

// ---- quad butterfly sum (sums within each group of 4 consecutive lanes) ----
// DPP quad_perm: [1,0,3,2]=0xB1 (xor1), [2,3,0,1]=0x4E (xor2). Pure VALU.
__device__ __forceinline__ float quad_sum(float x) {
    int i = __builtin_amdgcn_mov_dpp(__float_as_int(x), 0xB1, 0xF, 0xF, true);
    x += __int_as_float(i);
    i = __builtin_amdgcn_mov_dpp(__float_as_int(x), 0x4E, 0xF, 0xF, true);
    return x + __int_as_float(i);
}

// ---- K0: init out=bias, amax=0 (== -inf key), denom=0 ----
__global__ __launch_bounds__(256) void init_kernel(
    float* __restrict__ out, const float* __restrict__ bias,
    unsigned* __restrict__ amax, float* __restrict__ denom)
{
    int idx = blockIdx.x * 256 + threadIdx.x;
    if (idx < Nn * OUTC) out[idx] = bias[idx & (OUTC - 1)];
    if (idx < Nn * 4) { amax[idx] = 0u; denom[idx] = 0.f; }
}

// ---- K_pack: Wl/Wr/We -> MFMA B-frag order, bf16, permuted columns ----
// Column permutation: tile T (0..15), tile-col l15 -> orig col l15*16 + T.
// So each lane's 16 tile-values (over T) cover 16 CONSECUTIVE orig columns,
// all within one head (head = l15>>2). Frag slot layout:
//   sid = kc*1024 + T*64 + lane ; k = kc*32 + (lane>>4)*8 + j ; col = (lane&15)*16 + T
__global__ __launch_bounds__(256) void pack_kernel(
    const float* __restrict__ Wl, const float* __restrict__ Wr,
    const float* __restrict__ We,
    unsigned short* __restrict__ wlf, unsigned short* __restrict__ wrf,
    unsigned short* __restrict__ wef)
{
    int sid = blockIdx.x * 256 + threadIdx.x;
    const float* W; unsigned short* dst; int s;
    if (sid < 4096)      { W = Wl; dst = wlf; s = sid; }
    else if (sid < 8192) { W = Wr; dst = wrf; s = sid - 4096; }
    else if (sid < 9216) { W = We; dst = wef; s = sid - 8192; }
    else return;
    int lane = s & 63;
    int T    = (s >> 6) & 15;
    int kc   = s >> 10;                       // 0..3 (Wl/Wr), 0 (We)
    int col  = (lane & 15) * 16 + T;
    int k0   = kc * 32 + (lane >> 4) * 8;
    unsigned short tmp[8];
    #pragma unroll
    for (int j = 0; j < 8; ++j) tmp[j] = f2bf(W[(size_t)(k0 + j) * HC + col]);
    *(uint4*)(dst + (size_t)s * 8) = *(uint4*)tmp;
}

// ---- K1: Y = bf16(X @ W + b) via MFMA, no LDS ----
// blockIdx.y: 0 -> (wlf,bl)->xlb, 1 -> (wrf,br)->xrb.
// Wave = 16 rows x 256 cols: acc[16 tiles] f32x4; A row = l15, k = kc*32+l4*8+j.
// Output written in ORIGINAL column order (lane stores cols l15*16..+15).
__global__ __launch_bounds__(256) void gemm_kernel(
    const float* __restrict__ X,
    const unsigned short* __restrict__ wlf, const float* __restrict__ bl,
    const unsigned short* __restrict__ wrf, const float* __restrict__ br,
    unsigned short* __restrict__ Ylb, unsigned short* __restrict__ Yrb)
{
    const unsigned short* wf; const float* b; unsigned short* Yb;
    if (blockIdx.y == 0) { wf = wlf; b = bl; Yb = Ylb; } else { wf = wrf; b = br; Yb = Yrb; }

    const int tid = threadIdx.x, lane = tid & 63;
    const int l15 = lane & 15, l4 = lane >> 4;
    const int r0 = blockIdx.x * 64 + (tid >> 6) * 16;

    int arow = r0 + l15; if (arow >= Nn) arow = Nn - 1;
    short8 af[4];
    #pragma unroll
    for (int kc = 0; kc < 4; ++kc) {
        const f32x4* p = (const f32x4*)(X + (size_t)arow * INC + kc * 32 + l4 * 8);
        f32x4 v0 = p[0], v1 = p[1];
        short8 a;
        a[0]=(short)f2bf(v0.x); a[1]=(short)f2bf(v0.y); a[2]=(short)f2bf(v0.z); a[3]=(short)f2bf(v0.w);
        a[4]=(short)f2bf(v1.x); a[5]=(short)f2bf(v1.y); a[6]=(short)f2bf(v1.z); a[7]=(short)f2bf(v1.w);
        af[kc] = a;
    }

    f32x4 acc[16];
    #pragma unroll
    for (int T = 0; T < 16; ++T) acc[T] = (f32x4){0.f, 0.f, 0.f, 0.f};

    #pragma unroll
    for (int kc = 0; kc < 4; ++kc) {
        #pragma unroll
        for (int T = 0; T < 16; ++T) {
            short8 bf = *(const short8*)(wf + ((size_t)(kc * 16 + T) * 64 + lane) * 8);
            acc[T] = __builtin_amdgcn_mfma_f32_16x16x32_bf16(af[kc], bf, acc[T], 0, 0, 0);
        }
    }

    float bb[16];
    #pragma unroll
    for (int t4 = 0; t4 < 4; ++t4) {
        float4 v = *(const float4*)(b + l15 * 16 + t4 * 4);
        bb[t4*4+0]=v.x; bb[t4*4+1]=v.y; bb[t4*4+2]=v.z; bb[t4*4+3]=v.w;
    }

    #pragma unroll
    for (int r = 0; r < 4; ++r) {
        int orow = r0 + l4 * 4 + r;
        if (orow < Nn) {
            unsigned short o[16];
            #pragma unroll
            for (int T = 0; T < 16; ++T) o[T] = f2bf(acc[T][r] + bb[T]);
            *(uint4*)(Yb + (size_t)orow * HC + l15 * 16)     = *(uint4*)(o);
            *(uint4*)(Yb + (size_t)orow * HC + l15 * 16 + 8) = *(uint4*)(o + 8);
        }
    }
}

// ---- K2: per-edge logits via MFMA bf16 + quad-DPP reduce, no LDS ----
// Wave = 16 edges (A row = l15 = edge). acc[T][r]: edge l4*4+r, orig col l15*16+T.
// Lane's 16 cols are consecutive AND single-head (h=l15>>2): gathers are 2x16B,
// head-reduce = sum over 4-lane quad (2 DPP adds). Every lane in the quad ends
// with alpha[e,h]; lane l15%4==0 writes + atomicMax.
__global__ __launch_bounds__(256) void edge_alpha_kernel(
    const unsigned short* __restrict__ xlb, const unsigned short* __restrict__ xrb,
    const int* __restrict__ ei, const float* __restrict__ ea,
    const unsigned short* __restrict__ wef, const float* __restrict__ att,
    float* __restrict__ alpha, unsigned* __restrict__ amax)
{
    const int tid = threadIdx.x, lane = tid & 63;
    const int l15 = lane & 15, l4 = lane >> 4;
    const int e0 = blockIdx.x * 64 + (tid >> 6) * 16;

    // A-frag: ea[e0+l15][l4*8+j], nontemporal (streamed once)
    int eA = e0 + l15; if (eA >= Ee) eA = Ee - 1;
    const f32x4* p = (const f32x4*)(ea + (size_t)eA * EDIM + l4 * 8);
    f32x4 v0 = __builtin_nontemporal_load(p);
    f32x4 v1 = __builtin_nontemporal_load(p + 1);
    short8 af;
    af[0]=(short)f2bf(v0.x); af[1]=(short)f2bf(v0.y); af[2]=(short)f2bf(v0.z); af[3]=(short)f2bf(v0.w);
    af[4]=(short)f2bf(v1.x); af[5]=(short)f2bf(v1.y); af[6]=(short)f2bf(v1.z); af[7]=(short)f2bf(v1.w);

    f32x4 acc[16];
    #pragma unroll
    for (int T = 0; T < 16; ++T) {
        short8 bf = *(const short8*)(wef + ((size_t)T * 64 + lane) * 8);
        const f32x4 z = {0.f, 0.f, 0.f, 0.f};
        acc[T] = __builtin_amdgcn_mfma_f32_16x16x32_bf16(af, bf, z, 0, 0, 0);
    }

    // att for this lane's 16 consecutive cols (single head)
    float at[16];
    const float* ap = att + (l15 >> 2) * 64 + (l15 & 3) * 16;
    #pragma unroll
    for (int t4 = 0; t4 < 4; ++t4) {
        float4 v = *(const float4*)(ap + t4 * 4);
        at[t4*4+0]=v.x; at[t4*4+1]=v.y; at[t4*4+2]=v.z; at[t4*4+3]=v.w;
    }
    const int h = l15 >> 2;

    #pragma unroll
    for (int r = 0; r < 4; ++r) {
        int e = e0 + l4 * 4 + r;
        int ec = (e < Ee) ? e : Ee - 1;
        int sn = ei[ec], dn = ei[Ee + ec];
        const unsigned short* ps = xlb + (size_t)sn * HC + l15 * 16;
        const unsigned short* pd = xrb + (size_t)dn * HC + l15 * 16;
        short8 gl0 = *(const short8*)ps;
        short8 gl1 = *(const short8*)(ps + 8);
        short8 gr0 = *(const short8*)pd;
        short8 gr1 = *(const short8*)(pd + 8);
        float pa = 0.f;
        #pragma unroll
        for (int T = 0; T < 8; ++T) {
            float m = acc[T][r] + bf2f((unsigned short)gl0[T]) + bf2f((unsigned short)gr0[T]);
            m = fmaxf(m, NEG * m);
            pa = fmaf(at[T], m, pa);
        }
        #pragma unroll
        for (int T = 8; T < 16; ++T) {
            float m = acc[T][r] + bf2f((unsigned short)gl1[T-8]) + bf2f((unsigned short)gr1[T-8]);
            m = fmaxf(m, NEG * m);
            pa = fmaf(at[T], m, pa);
        }
        pa = quad_sum(pa);
        if ((l15 & 3) == 0 && e < Ee) {
            alpha[(size_t)e * 4 + h] = pa;
            atomicMax(amax + (size_t)dn * 4 + h, fenc(pa));
        }
    }
}

// ---- K3: alpha <- exp(alpha - amax[dst]); denom[dst] += alpha ----
__global__ __launch_bounds__(256) void edge_exp_kernel(
    const int* __restrict__ ei, float* __restrict__ alpha,
    const unsigned* __restrict__ amax, float* __restrict__ denom)
{
    int idx = blockIdx.x * 256 + threadIdx.x;
    if (idx >= Ee * 4) return;
    int e = idx >> 2, hh = idx & 3;
    int d = ei[Ee + e];
    float mx = fdec(amax[(size_t)d * 4 + hh]);
    float v = __expf(alpha[idx] - mx);
    alpha[idx] = v;
    atomicAdd(denom + (size_t)d * 4 + hh, v);
}

// ---- K4: out[dst,c] += 0.25 * sum_h (alpha/denom) * xlb[src,h,c] ----
__global__ __launch_bounds__(256) void edge_aggr_kernel(
    const unsigned short* __restrict__ xlb, const int* __restrict__ ei,
    const float* __restrict__ alpha, const float* __restrict__ denom,
    float* __restrict__ out)
{
    int lane = threadIdx.x & 63;
    int e = blockIdx.x * 4 + (threadIdx.x >> 6);
    if (e >= Ee) return;
    int s = ei[e], d = ei[Ee + e];
    float acc = 0.f;
    #pragma unroll
    for (int hh = 0; hh < 4; ++hh) {
        float w = 0.25f * alpha[(size_t)e * 4 + hh] / denom[(size_t)d * 4 + hh];
        acc = fmaf(w, bf2f(xlb[(size_t)s * HC + hh * OUTC + lane]), acc);
    }
    atomicAdd(out + (size_t)d * OUTC + lane, acc);
}

extern "C" void kernel_launch(void* const* d_in, const int* in_sizes, int n_in,
                              void* d_out, int out_size, void* d_ws, size_t ws_size,
                              hipStream_t stream)
{
    const float* x    = (const float*)d_in[0];
    const int*   ei   = (const int*)d_in[1];
    const float* ea   = (const float*)d_in[2];
    const float* Wl   = (const float*)d_in[3];
    const float* bl   = (const float*)d_in[4];
    const float* Wr   = (const float*)d_in[5];
    const float* br   = (const float*)d_in[6];
    const float* We   = (const float*)d_in[7];
    const float* att  = (const float*)d_in[8];
    const float* bias = (const float*)d_in[9];
    float* out = (float*)d_out;

    // workspace layout (~60 MB)
    unsigned short* xlb   = (unsigned short*)d_ws;                 // N*256 bf16
    unsigned short* xrb   = xlb + (size_t)Nn * HC;                 // N*256 bf16
    float*          alpha = (float*)(xrb + (size_t)Nn * HC);       // E*4 f32
    unsigned*       amax  = (unsigned*)(alpha + (size_t)Ee * 4);   // N*4 u32
    float*          denom = (float*)(amax + (size_t)Nn * 4);       // N*4 f32
    unsigned short* wef   = (unsigned short*)(denom + (size_t)Nn * 4); // 8192 bf16
    unsigned short* wlf   = wef + 8192;                            // 32768 bf16
    unsigned short* wrf   = wlf + 32768;                           // 32768 bf16

    init_kernel<<<(Nn * OUTC + 255) / 256, 256, 0, stream>>>(out, bias, amax, denom);
    pack_kernel<<<36, 256, 0, stream>>>(Wl, Wr, We, wlf, wrf, wef);
    gemm_kernel<<<dim3((Nn + 63) / 64, 2), 256, 0, stream>>>(x, wlf, bl, wrf, br, xlb, xrb);
    edge_alpha_kernel<<<(Ee + 63) / 64, 256, 0, stream>>>(xlb, xrb, ei, ea, wef, att, alpha, amax);
    edge_exp_kernel<<<(Ee * 4 + 255) / 256, 256, 0, stream>>>(ei, alpha, amax, denom);
    edge_aggr_kernel<<<(Ee + 3) / 4, 256, 0, stream>>>(xlb, ei, alpha, denom, out);
}

// Round 9
// 293.884 us; speedup vs baseline: 1.2246x; 1.1328x over previous
//
#include <hip/hip_runtime.h>
#include <cstddef>

#define Nn 50000
#define Ee 500000
#define INC 128
#define HC 256      // HEADS*OUT_C
#define OUTC 64
#define EDIM 32
#define NEG 0.2f

typedef __attribute__((ext_vector_type(8))) short short8;   // 8 bf16 = 4 VGPR
typedef __attribute__((ext_vector_type(4))) float f32x4;

// ---- bf16 helpers (RNE) ----
__device__ __forceinline__ unsigned short f2bf(float f) {
    unsigned u = __float_as_uint(f);
    return (unsigned short)((u + 0x7FFFu + ((u >> 16) & 1u)) >> 16);
}
__device__ __forceinline__ float bf2f(unsigned short v) {
    return __uint_as_float(((unsigned)v) << 16);
}

// ---- ordered-uint encoding for float atomic max ----
__device__ __forceinline__ unsigned fenc(float f) {
    unsigned u = __float_as_uint(f);
    return (u & 0x80000000u) ? ~u : (u | 0x80000000u);
}
__device__ __forceinline__ float fdec(unsigned k) {
    unsigned u = (k & 0x80000000u) ? (k & 0x7FFFFFFFu) : ~k;
    return __uint_as_float(u);
}

// ---- 16-lane row sum via DPP butterfly (pure VALU, no DS pipe) ----
// quad_perm[1,0,3,2]=0xB1 (xor1), quad_perm[2,3,0,1]=0x4E (xor2),
// ROW_HALF_MIRROR=0x141 (quad<->quad), ROW_MIRROR=0x140 (half<->half).
__device__ __forceinline__ float row_sum16(float x) {
    int i;
    i = __builtin_amdgcn_mov_dpp(__float_as_int(x), 0xB1, 0xF, 0xF, true);
    x += __int_as_float(i);
    i = __builtin_amdgcn_mov_dpp(__float_as_int(x), 0x4E, 0xF, 0xF, true);
    x += __int_as_float(i);
    i = __builtin_amdgcn_mov_dpp(__float_as_int(x), 0x141, 0xF, 0xF, true);
    x += __int_as_float(i);
    i = __builtin_amdgcn_mov_dpp(__float_as_int(x), 0x140, 0xF, 0xF, true);
    x += __int_as_float(i);
    return x;
}

// ---- K0: init out=bias, amax=0 (== -inf key), denom=0 ----
__global__ __launch_bounds__(256) void init_kernel(
    float* __restrict__ out, const float* __restrict__ bias,
    unsigned* __restrict__ amax, float* __restrict__ denom)
{
    int idx = blockIdx.x * 256 + threadIdx.x;
    if (idx < Nn * OUTC) out[idx] = bias[idx & (OUTC - 1)];
    if (idx < Nn * 4) { amax[idx] = 0u; denom[idx] = 0.f; }
}

// ---- K_pack: Wl/Wr (T-perm, for gemm) + We (cb-perm, for edge_alpha) ----
// wlf/wrf: sid = kc*1024 + T*64 + lane ; k = kc*32+(lane>>4)*8+j ; col = (lane&15)*16+T
// wef:     sid = (cb*4+nt)*64 + lane   ; k = (lane>>4)*8+j       ; col = cb*64+(lane&15)*4+nt
__global__ __launch_bounds__(256) void pack_kernel(
    const float* __restrict__ Wl, const float* __restrict__ Wr,
    const float* __restrict__ We,
    unsigned short* __restrict__ wlf, unsigned short* __restrict__ wrf,
    unsigned short* __restrict__ wef)
{
    int sid = blockIdx.x * 256 + threadIdx.x;
    const float* W; unsigned short* dst; int s; int col; int k0;
    if (sid < 8192) {
        if (sid < 4096) { W = Wl; dst = wlf; s = sid; }
        else            { W = Wr; dst = wrf; s = sid - 4096; }
        int lane = s & 63;
        int T    = (s >> 6) & 15;
        int kc   = s >> 10;
        col = (lane & 15) * 16 + T;
        k0  = kc * 32 + (lane >> 4) * 8;
    } else if (sid < 9216) {
        W = We; dst = wef; s = sid - 8192;
        int lane = s & 63;
        int nt   = (s >> 6) & 3;
        int cb   = s >> 8;
        col = cb * 64 + (lane & 15) * 4 + nt;
        k0  = (lane >> 4) * 8;
    } else return;
    unsigned short tmp[8];
    #pragma unroll
    for (int j = 0; j < 8; ++j) tmp[j] = f2bf(W[(size_t)(k0 + j) * HC + col]);
    *(uint4*)(dst + (size_t)s * 8) = *(uint4*)tmp;
}

// ---- K1: Y = bf16(X @ W + b) via MFMA, no LDS (R8 version, kept) ----
__global__ __launch_bounds__(256) void gemm_kernel(
    const float* __restrict__ X,
    const unsigned short* __restrict__ wlf, const float* __restrict__ bl,
    const unsigned short* __restrict__ wrf, const float* __restrict__ br,
    unsigned short* __restrict__ Ylb, unsigned short* __restrict__ Yrb)
{
    const unsigned short* wf; const float* b; unsigned short* Yb;
    if (blockIdx.y == 0) { wf = wlf; b = bl; Yb = Ylb; } else { wf = wrf; b = br; Yb = Yrb; }

    const int tid = threadIdx.x, lane = tid & 63;
    const int l15 = lane & 15, l4 = lane >> 4;
    const int r0 = blockIdx.x * 64 + (tid >> 6) * 16;

    int arow = r0 + l15; if (arow >= Nn) arow = Nn - 1;
    short8 af[4];
    #pragma unroll
    for (int kc = 0; kc < 4; ++kc) {
        const f32x4* p = (const f32x4*)(X + (size_t)arow * INC + kc * 32 + l4 * 8);
        f32x4 v0 = p[0], v1 = p[1];
        short8 a;
        a[0]=(short)f2bf(v0.x); a[1]=(short)f2bf(v0.y); a[2]=(short)f2bf(v0.z); a[3]=(short)f2bf(v0.w);
        a[4]=(short)f2bf(v1.x); a[5]=(short)f2bf(v1.y); a[6]=(short)f2bf(v1.z); a[7]=(short)f2bf(v1.w);
        af[kc] = a;
    }

    f32x4 acc[16];
    #pragma unroll
    for (int T = 0; T < 16; ++T) acc[T] = (f32x4){0.f, 0.f, 0.f, 0.f};

    #pragma unroll
    for (int kc = 0; kc < 4; ++kc) {
        #pragma unroll
        for (int T = 0; T < 16; ++T) {
            short8 bf = *(const short8*)(wf + ((size_t)(kc * 16 + T) * 64 + lane) * 8);
            acc[T] = __builtin_amdgcn_mfma_f32_16x16x32_bf16(af[kc], bf, acc[T], 0, 0, 0);
        }
    }

    float bb[16];
    #pragma unroll
    for (int t4 = 0; t4 < 4; ++t4) {
        float4 v = *(const float4*)(b + l15 * 16 + t4 * 4);
        bb[t4*4+0]=v.x; bb[t4*4+1]=v.y; bb[t4*4+2]=v.z; bb[t4*4+3]=v.w;
    }

    #pragma unroll
    for (int r = 0; r < 4; ++r) {
        int orow = r0 + l4 * 4 + r;
        if (orow < Nn) {
            unsigned short o[16];
            #pragma unroll
            for (int T = 0; T < 16; ++T) o[T] = f2bf(acc[T][r] + bb[T]);
            *(uint4*)(Yb + (size_t)orow * HC + l15 * 16)     = *(uint4*)(o);
            *(uint4*)(Yb + (size_t)orow * HC + l15 * 16 + 8) = *(uint4*)(o + 8);
        }
    }
}

// ---- K2: per-edge logits via MFMA bf16, no LDS, DPP 16-lane reduce ----
// R7 structure (wave = 32 edges, cb-loop, VGPR<=64) with shfl chain replaced
// by row_sum16 DPP butterfly. att loaded inside cb-loop to keep reg pressure.
__global__ __launch_bounds__(256) void edge_alpha_kernel(
    const unsigned short* __restrict__ xlb, const unsigned short* __restrict__ xrb,
    const int* __restrict__ ei, const float* __restrict__ ea,
    const unsigned short* __restrict__ wef, const float* __restrict__ att,
    float* __restrict__ alpha, unsigned* __restrict__ amax)
{
    const int tid  = threadIdx.x;
    const int lane = tid & 63;
    const int l15  = lane & 15, l4 = lane >> 4;
    const int e0   = blockIdx.x * 128 + (tid >> 6) * 32;

    // A-frags: 2 tiles of 16 edges; nontemporal (ea streamed once)
    short8 afrag[2];
    #pragma unroll
    for (int mt = 0; mt < 2; ++mt) {
        int e = e0 + mt * 16 + l15;
        if (e >= Ee) e = Ee - 1;
        const f32x4* p = (const f32x4*)(ea + (size_t)e * EDIM + l4 * 8);
        f32x4 v0 = __builtin_nontemporal_load(p);
        f32x4 v1 = __builtin_nontemporal_load(p + 1);
        short8 a;
        a[0]=(short)f2bf(v0.x); a[1]=(short)f2bf(v0.y); a[2]=(short)f2bf(v0.z); a[3]=(short)f2bf(v0.w);
        a[4]=(short)f2bf(v1.x); a[5]=(short)f2bf(v1.y); a[6]=(short)f2bf(v1.z); a[7]=(short)f2bf(v1.w);
        afrag[mt] = a;
    }

    // per-slot node row offsets (slot = mt*4 + r)
    unsigned soff[8], doff[8];
    #pragma unroll
    for (int mt = 0; mt < 2; ++mt)
        #pragma unroll
        for (int r = 0; r < 4; ++r) {
            int idx = mt * 4 + r;
            int e = e0 + mt * 16 + l4 * 4 + r;
            int ec = (e < Ee) ? e : Ee - 1;
            soff[idx] = (unsigned)ei[ec] * (unsigned)HC;
            doff[idx] = (unsigned)ei[Ee + ec] * (unsigned)HC;
        }

    #pragma unroll 1
    for (int cb = 0; cb < 4; ++cb) {
        short8 bfrag[4];
        #pragma unroll
        for (int nt = 0; nt < 4; ++nt)
            bfrag[nt] = *(const short8*)(wef + ((size_t)(cb * 4 + nt) * 64 + lane) * 8);

        f32x4 acc[2][4];
        const f32x4 z = {0.f, 0.f, 0.f, 0.f};
        #pragma unroll
        for (int mt = 0; mt < 2; ++mt)
            #pragma unroll
            for (int nt = 0; nt < 4; ++nt)
                acc[mt][nt] = __builtin_amdgcn_mfma_f32_16x16x32_bf16(
                    afrag[mt], bfrag[nt], z, 0, 0, 0);

        float4 atv = *(const float4*)(att + cb * 64 + l15 * 4);

        #pragma unroll
        for (int mt = 0; mt < 2; ++mt) {
            #pragma unroll
            for (int r = 0; r < 4; ++r) {
                const int idx = mt * 4 + r;
                const unsigned c = (unsigned)(cb * 64 + l15 * 4);
                ushort4 gl4 = *(const ushort4*)(xlb + soff[idx] + c);
                ushort4 gr4 = *(const ushort4*)(xrb + doff[idx] + c);
                float m0 = acc[mt][0][r] + bf2f(gl4.x) + bf2f(gr4.x);
                float m1 = acc[mt][1][r] + bf2f(gl4.y) + bf2f(gr4.y);
                float m2 = acc[mt][2][r] + bf2f(gl4.z) + bf2f(gr4.z);
                float m3 = acc[mt][3][r] + bf2f(gl4.w) + bf2f(gr4.w);
                m0 = fmaxf(m0, NEG * m0);
                m1 = fmaxf(m1, NEG * m1);
                m2 = fmaxf(m2, NEG * m2);
                m3 = fmaxf(m3, NEG * m3);
                float p;
                p = atv.x * m0;
                p = fmaf(atv.y, m1, p);
                p = fmaf(atv.z, m2, p);
                p = fmaf(atv.w, m3, p);
                p = row_sum16(p);
                int e = e0 + mt * 16 + l4 * 4 + r;
                if (l15 == 0 && e < Ee) {
                    alpha[(size_t)e * 4 + cb] = p;
                    atomicMax(amax + (size_t)(doff[idx] >> 8) * 4 + cb, fenc(p));
                }
            }
        }
    }
}

// ---- K3: alpha <- exp(alpha - amax[dst]); denom[dst] += alpha ----
__global__ __launch_bounds__(256) void edge_exp_kernel(
    const int* __restrict__ ei, float* __restrict__ alpha,
    const unsigned* __restrict__ amax, float* __restrict__ denom)
{
    int idx = blockIdx.x * 256 + threadIdx.x;
    if (idx >= Ee * 4) return;
    int e = idx >> 2, hh = idx & 3;
    int d = ei[Ee + e];
    float mx = fdec(amax[(size_t)d * 4 + hh]);
    float v = __expf(alpha[idx] - mx);
    alpha[idx] = v;
    atomicAdd(denom + (size_t)d * 4 + hh, v);
}

// ---- K3b: denom <- 0.25/denom (hoists divide out of 32M aggr lanes) ----
__global__ __launch_bounds__(256) void inv_kernel(float* __restrict__ denom)
{
    int i = blockIdx.x * 256 + threadIdx.x;
    if (i < Nn * 4) denom[i] = 0.25f / denom[i];
}

// ---- K4: out[dst,c] += sum_h alpha*dinv * xlb[src,h,c] ----
__global__ __launch_bounds__(256) void edge_aggr_kernel(
    const unsigned short* __restrict__ xlb, const int* __restrict__ ei,
    const float* __restrict__ alpha, const float* __restrict__ dinv,
    float* __restrict__ out)
{
    int lane = threadIdx.x & 63;
    int e = blockIdx.x * 4 + (threadIdx.x >> 6);
    if (e >= Ee) return;
    int s = ei[e], d = ei[Ee + e];
    float acc = 0.f;
    #pragma unroll
    for (int hh = 0; hh < 4; ++hh) {
        float w = alpha[(size_t)e * 4 + hh] * dinv[(size_t)d * 4 + hh];
        acc = fmaf(w, bf2f(xlb[(size_t)s * HC + hh * OUTC + lane]), acc);
    }
    atomicAdd(out + (size_t)d * OUTC + lane, acc);
}

extern "C" void kernel_launch(void* const* d_in, const int* in_sizes, int n_in,
                              void* d_out, int out_size, void* d_ws, size_t ws_size,
                              hipStream_t stream)
{
    const float* x    = (const float*)d_in[0];
    const int*   ei   = (const int*)d_in[1];
    const float* ea   = (const float*)d_in[2];
    const float* Wl   = (const float*)d_in[3];
    const float* bl   = (const float*)d_in[4];
    const float* Wr   = (const float*)d_in[5];
    const float* br   = (const float*)d_in[6];
    const float* We   = (const float*)d_in[7];
    const float* att  = (const float*)d_in[8];
    const float* bias = (const float*)d_in[9];
    float* out = (float*)d_out;

    // workspace layout (~60 MB)
    unsigned short* xlb   = (unsigned short*)d_ws;                 // N*256 bf16
    unsigned short* xrb   = xlb + (size_t)Nn * HC;                 // N*256 bf16
    float*          alpha = (float*)(xrb + (size_t)Nn * HC);       // E*4 f32
    unsigned*       amax  = (unsigned*)(alpha + (size_t)Ee * 4);   // N*4 u32
    float*          denom = (float*)(amax + (size_t)Nn * 4);       // N*4 f32
    unsigned short* wef   = (unsigned short*)(denom + (size_t)Nn * 4); // 8192 bf16
    unsigned short* wlf   = wef + 8192;                            // 32768 bf16
    unsigned short* wrf   = wlf + 32768;                           // 32768 bf16

    init_kernel<<<(Nn * OUTC + 255) / 256, 256, 0, stream>>>(out, bias, amax, denom);
    pack_kernel<<<36, 256, 0, stream>>>(Wl, Wr, We, wlf, wrf, wef);
    gemm_kernel<<<dim3((Nn + 63) / 64, 2), 256, 0, stream>>>(x, wlf, bl, wrf, br, xlb, xrb);
    edge_alpha_kernel<<<(Ee + 127) / 128, 256, 0, stream>>>(xlb, xrb, ei, ea, wef, att, alpha, amax);
    edge_exp_kernel<<<(Ee * 4 + 255) / 256, 256, 0, stream>>>(ei, alpha, amax, denom);
    inv_kernel<<<(Nn * 4 + 255) / 256, 256, 0, stream>>>(denom);
    edge_aggr_kernel<<<(Ee + 3) / 4, 256, 0, stream>>>(xlb, ei, alpha, denom, out);
}